// Round 1
// baseline (309.996 us; speedup 1.0000x reference)
//
#include <hip/hip_runtime.h>
#include <math.h>

#define NP 1024
#define R 32
#define C 16

__device__ __forceinline__ float eluf(float x) {
    return x > 0.f ? expm1f(0.f) + x : expm1f(x);  // x>0 ? x : exp(x)-1
}

// ---------------------------------------------------------------------------
// Kernel A: layer-1 pair pass.
// out0[a]   = sum_b r00(a,b)                       (filter 0, unmasked, F=1)
// out1[a,i] = sum_b mask*r01(a,b)*unit_i(a,b)      (filter 1, masked,   F=1)
// One block per 'a', 256 threads stride 'b'.
// ---------------------------------------------------------------------------
__global__ __launch_bounds__(256) void k_layer1(
    const float* __restrict__ points,
    const float* __restrict__ W1, const float* __restrict__ B1,
    const float* __restrict__ W2, const float* __restrict__ B2,
    float* __restrict__ out0, float* __restrict__ out1)
{
    __shared__ float sW1[2*R*R];
    __shared__ float sB1[2*R];
    __shared__ float sW2[2*R];
    __shared__ float sB2[2];
    __shared__ float sred[4*4];
    const int tid = threadIdx.x;
    for (int i = tid; i < 2*R*R; i += 256) sW1[i] = W1[i];
    if (tid < 2*R) sB1[tid] = B1[tid];
    else if (tid < 4*R) sW2[tid - 2*R] = W2[tid - 2*R];
    if (tid < 2) sB2[tid] = B2[tid];
    const int a = blockIdx.x;
    const float pax = points[a*3+0], pay = points[a*3+1], paz = points[a*3+2];
    __syncthreads();

    float acc0 = 0.f, a1x = 0.f, a1y = 0.f, a1z = 0.f;
    for (int b = tid; b < NP; b += 256) {
        const float rx = pax - points[b*3+0];
        const float ry = pay - points[b*3+1];
        const float rz = paz - points[b*3+2];
        const float ss = rx*rx + ry*ry + rz*rz;
        const bool m0 = ss < 1e-8f;
        const float dij = m0 ? 0.f : sqrtf(ss);
        const float inv = 1.0f / sqrtf(fmaxf(ss, 1e-8f));
        const float ux = rx*inv, uy = ry*inv, uz = rz*inv;
        float rbf[R];
        #pragma unroll
        for (int k = 0; k < R; k++) {
            const float t = dij - (float)k * (3.5f/31.0f);
            rbf[k] = __expf(-(32.0f/3.5f) * t * t);
        }
        float r00 = sB2[0], r01 = sB2[1];
        #pragma unroll 4
        for (int j = 0; j < R; j++) {
            float s0 = sB1[j], s1 = sB1[R+j];
            #pragma unroll
            for (int k = 0; k < R; k++) {
                s0 = fmaf(rbf[k], sW1[k*R + j], s0);
                s1 = fmaf(rbf[k], sW1[R*R + k*R + j], s1);
            }
            r00 = fmaf(fmaxf(s0, 0.f), sW2[j],   r00);
            r01 = fmaf(fmaxf(s1, 0.f), sW2[R+j], r01);
        }
        acc0 += r00;
        if (!m0) {
            a1x = fmaf(r01, ux, a1x);
            a1y = fmaf(r01, uy, a1y);
            a1z = fmaf(r01, uz, a1z);
        }
    }
    #pragma unroll
    for (int off = 32; off > 0; off >>= 1) {
        acc0 += __shfl_down(acc0, off);
        a1x  += __shfl_down(a1x,  off);
        a1y  += __shfl_down(a1y,  off);
        a1z  += __shfl_down(a1z,  off);
    }
    const int lane = tid & 63, wv = tid >> 6;
    if (lane == 0) {
        sred[wv*4+0] = acc0; sred[wv*4+1] = a1x;
        sred[wv*4+2] = a1y;  sred[wv*4+3] = a1z;
    }
    __syncthreads();
    if (tid == 0) {
        float t0 = 0.f, t1 = 0.f, t2 = 0.f, t3 = 0.f;
        for (int w = 0; w < 4; w++) {
            t0 += sred[w*4+0]; t1 += sred[w*4+1];
            t2 += sred[w*4+2]; t3 += sred[w*4+3];
        }
        out0[a] = t0;
        out1[a*3+0] = t1; out1[a*3+1] = t2; out1[a*3+2] = t3;
    }
}

// ---------------------------------------------------------------------------
// Kernel B: per-point layer-1 features.
// x0[b,g] = elu(out0[b]*si0_w[g] + si0_b[g])
// t[g,i]  = out1[b,i]*si1_w[g];  x1[b,g,i] = t * elu(|t|+nl_b[g])/|t|
// ---------------------------------------------------------------------------
__global__ __launch_bounds__(256) void k_point1(
    const float* __restrict__ out0, const float* __restrict__ out1,
    const float* __restrict__ si0_w, const float* __restrict__ si0_b,
    const float* __restrict__ si1_w, const float* __restrict__ nl_b,
    float* __restrict__ x0, float* __restrict__ x1)
{
    const int b = blockIdx.x*256 + threadIdx.x;
    if (b >= NP) return;
    const float o0 = out0[b];
    const float o1x = out1[b*3+0], o1y = out1[b*3+1], o1z = out1[b*3+2];
    #pragma unroll
    for (int g = 0; g < C; g++) {
        x0[b*C+g] = eluf(fmaf(o0, si0_w[g], si0_b[g]));
        const float w = si1_w[g];
        const float tx = o1x*w, ty = o1y*w, tz = o1z*w;
        const float n = sqrtf(fmaxf(tx*tx + ty*ty + tz*tz, 1e-8f));
        const float sc = eluf(n + nl_b[g]) / n;
        x1[(b*C+g)*3+0] = tx*sc;
        x1[(b*C+g)*3+1] = ty*sc;
        x1[(b*C+g)*3+2] = tz*sc;
    }
}

// ---------------------------------------------------------------------------
// Kernel C: layer-2 pair pass. ONLY filters 0 (0x0->0) and 2 (1x1->0) are
// live — the degree-1 layer-2 outputs are dead code in the reference.
// c00[a,f] = sum_b rad0(a,b,f) * x0[b,f]
// c10[a,f] = sum_b mask*rad2(a,b,f) * dot(unit(a,b), x1[b,f,:])
// ---------------------------------------------------------------------------
__global__ __launch_bounds__(256) void k_layer2(
    const float* __restrict__ points,
    const float* __restrict__ W1, const float* __restrict__ B1,
    const float* __restrict__ W2, const float* __restrict__ B2,
    const float* __restrict__ x0, const float* __restrict__ x1,
    float* __restrict__ c00, float* __restrict__ c10)
{
    __shared__ float sW1[2*R*R];
    __shared__ float sB1[2*R];
    __shared__ float sW2[2*R*C];
    __shared__ float sB2[2*C];
    __shared__ float sred[4*2*C];
    const int tid = threadIdx.x;
    for (int i = tid; i < R*R; i += 256) {          // filters 0 and 2
        sW1[i]       = W1[i];
        sW1[R*R + i] = W1[2*R*R + i];
    }
    for (int i = tid; i < R*C; i += 256) {
        sW2[i]       = W2[i];
        sW2[R*C + i] = W2[2*R*C + i];
    }
    if (tid < R) { sB1[tid] = B1[tid]; sB1[R+tid] = B1[2*R+tid]; }
    if (tid < C) { sB2[tid] = B2[tid]; sB2[C+tid] = B2[2*C+tid]; }
    const int a = blockIdx.x;
    const float pax = points[a*3+0], pay = points[a*3+1], paz = points[a*3+2];
    __syncthreads();

    float acc00[C], acc10[C];
    #pragma unroll
    for (int f = 0; f < C; f++) { acc00[f] = 0.f; acc10[f] = 0.f; }

    for (int b = tid; b < NP; b += 256) {
        const float rx = pax - points[b*3+0];
        const float ry = pay - points[b*3+1];
        const float rz = paz - points[b*3+2];
        const float ss = rx*rx + ry*ry + rz*rz;
        const bool m0 = ss < 1e-8f;
        const float dij = m0 ? 0.f : sqrtf(ss);
        const float inv = 1.0f / sqrtf(fmaxf(ss, 1e-8f));
        const float ux = rx*inv, uy = ry*inv, uz = rz*inv;
        float rbf[R];
        #pragma unroll
        for (int k = 0; k < R; k++) {
            const float t = dij - (float)k * (3.5f/31.0f);
            rbf[k] = __expf(-(32.0f/3.5f) * t * t);
        }
        float h[R];
        // filter 0 (unmasked)
        #pragma unroll 4
        for (int j = 0; j < R; j++) {
            float s = sB1[j];
            #pragma unroll
            for (int k = 0; k < R; k++) s = fmaf(rbf[k], sW1[k*R + j], s);
            h[j] = fmaxf(s, 0.f);
        }
        #pragma unroll 4
        for (int f = 0; f < C; f++) {
            float r = sB2[f];
            #pragma unroll
            for (int j = 0; j < R; j++) r = fmaf(h[j], sW2[j*C + f], r);
            acc00[f] = fmaf(r, x0[b*C + f], acc00[f]);
        }
        // filter 2 (masked; unit==0 on diagonal anyway)
        if (!m0) {
            #pragma unroll 4
            for (int j = 0; j < R; j++) {
                float s = sB1[R + j];
                #pragma unroll
                for (int k = 0; k < R; k++) s = fmaf(rbf[k], sW1[R*R + k*R + j], s);
                h[j] = fmaxf(s, 0.f);
            }
            #pragma unroll 4
            for (int f = 0; f < C; f++) {
                float r = sB2[C + f];
                #pragma unroll
                for (int j = 0; j < R; j++) r = fmaf(h[j], sW2[R*C + j*C + f], r);
                const float vx = x1[(b*C+f)*3+0];
                const float vy = x1[(b*C+f)*3+1];
                const float vz = x1[(b*C+f)*3+2];
                const float ud = ux*vx + uy*vy + uz*vz;
                acc10[f] = fmaf(r, ud, acc10[f]);
            }
        }
    }
    #pragma unroll
    for (int off = 32; off > 0; off >>= 1) {
        #pragma unroll
        for (int f = 0; f < C; f++) {
            acc00[f] += __shfl_down(acc00[f], off);
            acc10[f] += __shfl_down(acc10[f], off);
        }
    }
    const int lane = tid & 63, wv = tid >> 6;
    if (lane == 0) {
        #pragma unroll
        for (int f = 0; f < C; f++) {
            sred[wv*2*C + f]     = acc00[f];
            sred[wv*2*C + C + f] = acc10[f];
        }
    }
    __syncthreads();
    if (tid < 2*C) {
        const float s = sred[tid] + sred[2*C + tid] + sred[4*C + tid] + sred[6*C + tid];
        if (tid < C) c00[a*C + tid] = s;
        else         c10[a*C + (tid - C)] = s;
    }
}

// ---------------------------------------------------------------------------
// Kernel D1: per-point layer-2 degree-0 features + partial mean pool.
// x0n[a,g] = elu( sum_f c00[a,f]*w[g,f] + c10[a,f]*w[g,C+f] + b[g] )
// partial[blk][g] = sum over this block's a of x0n[a,g]
// ---------------------------------------------------------------------------
__global__ __launch_bounds__(256) void k_readout1(
    const float* __restrict__ c00, const float* __restrict__ c10,
    const float* __restrict__ si0_w, const float* __restrict__ si0_b,
    float* __restrict__ partial)
{
    __shared__ float sred[4*C];
    const int tid = threadIdx.x;
    const int a = blockIdx.x*256 + tid;
    float v00[C], v10[C];
    #pragma unroll
    for (int f = 0; f < C; f++) { v00[f] = c00[a*C+f]; v10[f] = c10[a*C+f]; }
    float xg[C];
    #pragma unroll
    for (int g = 0; g < C; g++) {
        float s = si0_b[g];
        #pragma unroll
        for (int f = 0; f < C; f++) s = fmaf(v00[f], si0_w[g*2*C + f], s);
        #pragma unroll
        for (int f = 0; f < C; f++) s = fmaf(v10[f], si0_w[g*2*C + C + f], s);
        xg[g] = eluf(s);
    }
    #pragma unroll
    for (int off = 32; off > 0; off >>= 1) {
        #pragma unroll
        for (int g = 0; g < C; g++) xg[g] += __shfl_down(xg[g], off);
    }
    const int lane = tid & 63, wv = tid >> 6;
    if (lane == 0) {
        #pragma unroll
        for (int g = 0; g < C; g++) sred[wv*C + g] = xg[g];
    }
    __syncthreads();
    if (tid < C) {
        partial[blockIdx.x*C + tid] =
            sred[tid] + sred[C + tid] + sred[2*C + tid] + sred[3*C + tid];
    }
}

// ---------------------------------------------------------------------------
// Kernel D2: final FC.  out[o] = fc_b[o] + sum_g mean_g * fc_w[g,o]
// ---------------------------------------------------------------------------
__global__ void k_readout2(const float* __restrict__ partial,
                           const float* __restrict__ fc_w,
                           const float* __restrict__ fc_b,
                           float* __restrict__ out)
{
    const int o = threadIdx.x;
    if (o < 8) {
        float s = fc_b[o];
        #pragma unroll
        for (int g = 0; g < C; g++) {
            const float m = (partial[g] + partial[C+g] + partial[2*C+g] + partial[3*C+g])
                            * (1.0f / (float)NP);
            s = fmaf(m, fc_w[g*8 + o], s);
        }
        out[o] = s;
    }
}

extern "C" void kernel_launch(void* const* d_in, const int* in_sizes, int n_in,
                              void* d_out, int out_size, void* d_ws, size_t ws_size,
                              hipStream_t stream)
{
    (void)in_sizes; (void)n_in; (void)out_size; (void)ws_size;
    const float* points   = (const float*)d_in[0];
    const float* l1_W1    = (const float*)d_in[1];
    const float* l1_B1    = (const float*)d_in[2];
    const float* l1_W2    = (const float*)d_in[3];
    const float* l1_B2    = (const float*)d_in[4];
    const float* l1_si0_w = (const float*)d_in[5];
    const float* l1_si0_b = (const float*)d_in[6];
    const float* l1_si1_w = (const float*)d_in[7];
    const float* l1_nl_b  = (const float*)d_in[8];
    const float* l2_W1    = (const float*)d_in[9];
    const float* l2_B1    = (const float*)d_in[10];
    const float* l2_W2    = (const float*)d_in[11];
    const float* l2_B2    = (const float*)d_in[12];
    const float* l2_si0_w = (const float*)d_in[13];
    const float* l2_si0_b = (const float*)d_in[14];
    // d_in[15] l2_si1_w, d_in[16] l2_nl_b: dead code in the reference readout
    const float* fc_w     = (const float*)d_in[17];
    const float* fc_b     = (const float*)d_in[18];

    float* ws      = (float*)d_ws;
    float* out0    = ws;                    // NP
    float* out1    = out0 + NP;             // NP*3
    float* x0      = out1 + NP*3;           // NP*C
    float* x1      = x0 + NP*C;             // NP*C*3
    float* c00     = x1 + NP*C*3;           // NP*C
    float* c10     = c00 + NP*C;            // NP*C
    float* partial = c10 + NP*C;            // 4*C

    k_layer1<<<NP, 256, 0, stream>>>(points, l1_W1, l1_B1, l1_W2, l1_B2, out0, out1);
    k_point1<<<NP/256, 256, 0, stream>>>(out0, out1, l1_si0_w, l1_si0_b, l1_si1_w, l1_nl_b, x0, x1);
    k_layer2<<<NP, 256, 0, stream>>>(points, l2_W1, l2_B1, l2_W2, l2_B2, x0, x1, c00, c10);
    k_readout1<<<NP/256, 256, 0, stream>>>(c00, c10, l2_si0_w, l2_si0_b, partial);
    k_readout2<<<1, 64, 0, stream>>>(partial, fc_w, fc_b, (float*)d_out);
}